// Round 3
// baseline (339.733 us; speedup 1.0000x reference)
//
#include <hip/hip_runtime.h>

// VQ-VAE forward on MI355X, fp32 (no fp32 MFMA on CDNA4 -> vector ALU).
// N = 65536 rows, IN_DIM=256, D=64, K=512.
//
// ws layout (bytes):
//   z:      float[65536*64]  @ 0          (16 MiB)
//   idx:    int[65536]       @ 16777216   (256 KiB)
//   cr:     float[512*256]   @ 17039360   (512 KiB)  = codebook @ dec_w
//   sse:    double           @ 17563648
//   counts: int[512]         @ 17563656   (2 KiB)
//   ees:    float[512]       @ 17565704   (2 KiB)    = ||e_k||^2 (ref fma order)

__device__ __forceinline__ unsigned ford(float s) {
    // order-preserving map float -> unsigned (total order, matches < on floats)
    unsigned b = __float_as_uint(s);
    return (b & 0x80000000u) ? ~b : (b | 0x80000000u);
}

// ---------------- K1: z = x @ enc_w  ([65536,256]x[256,64]) ----------------
// 512 blocks x 128 threads (2 waves). Wave = 64 rows x 64 d; lane tile 8x8.
// K chunked by 64 (4 chunks). Padded LDS (17-float4 stride) -> conflict-free.
// Accumulation order identical to round-2 kernel (bit-stable z).
__global__ __launch_bounds__(128, 2) void k_encode(const float* __restrict__ x,
                                                   const float* __restrict__ enc_w,
                                                   float* __restrict__ z) {
    __shared__ float xs[128 * 68];  // [row][k-chunk 64 +pad], 34816 B
    __shared__ float wEs[64 * 68];  // [d][k-chunk 64 +pad] (transposed), 17408 B

    int t = threadIdx.x;
    int w = t >> 6, lane = t & 63;
    int rg = lane >> 3, cg = lane & 7;
    int row0 = blockIdx.x * 128;

    const float4* xg4 = (const float4*)x;      // row stride 64 f4
    const float4* wg4 = (const float4*)enc_w;  // [256k][16 f4 of d]
    float4* xs4 = (float4*)xs;                 // stride 17 f4
    float4* wEs4 = (float4*)wEs;

    float acc[8][8];
#pragma unroll
    for (int r = 0; r < 8; ++r)
#pragma unroll
        for (int c = 0; c < 8; ++c) acc[r][c] = 0.f;

    for (int cc = 0; cc < 4; ++cc) {
        __syncthreads();
        // stage x chunk: 128 rows x 16 f4
        for (int i = t; i < 2048; i += 128) {
            int r = i >> 4, c = i & 15;
            xs4[r * 17 + c] = xg4[(size_t)(row0 + r) * 64 + cc * 16 + c];
        }
        // stage enc_w chunk transposed: [64 k][64 d] -> wEs[d][k]
        for (int i = t; i < 1024; i += 128) {
            int kk = i >> 4, cq = i & 15;
            float4 v = wg4[(cc * 64 + kk) * 16 + cq];
            wEs[(4 * cq + 0) * 68 + kk] = v.x;
            wEs[(4 * cq + 1) * 68 + kk] = v.y;
            wEs[(4 * cq + 2) * 68 + kk] = v.z;
            wEs[(4 * cq + 3) * 68 + kk] = v.w;
        }
        __syncthreads();

        for (int k4 = 0; k4 < 16; ++k4) {
            float4 wv[8];
#pragma unroll
            for (int c = 0; c < 8; ++c) wv[c] = wEs4[(cg + 8 * c) * 17 + k4];
#pragma unroll
            for (int r = 0; r < 8; ++r) {
                float4 xv = xs4[(w * 64 + rg + 8 * r) * 17 + k4];
#pragma unroll
                for (int c = 0; c < 8; ++c)
                    acc[r][c] = fmaf(xv.w, wv[c].w, fmaf(xv.z, wv[c].z,
                                fmaf(xv.y, wv[c].y, fmaf(xv.x, wv[c].x, acc[r][c]))));
            }
        }
    }
#pragma unroll
    for (int r = 0; r < 8; ++r) {
        int row = row0 + w * 64 + rg + 8 * r;
#pragma unroll
        for (int c = 0; c < 8; ++c) z[(size_t)row * 64 + cg + 8 * c] = acc[r][c];
    }
}

// ---------------- K2: nearest-code assignment + loss/hist ----------------
// 1024 blocks x 128 threads (2 waves). Block = 64 rows; wave w covers 64 codes
// of each 128-code chunk (4 chunks). Lane tile 8 rows x 8 codes.
__global__ __launch_bounds__(128, 2) void k_assign(const float* __restrict__ z,
                                                   const float* __restrict__ cb,
                                                   const float* __restrict__ ees_g,
                                                   int* __restrict__ idx,
                                                   double* __restrict__ sse,
                                                   int* __restrict__ counts) {
    __shared__ float zs[64 * 68];     // [row][64k +pad], 17408 B
    __shared__ float cbs[128 * 68];   // [code][64k +pad], 34816 B
    __shared__ float zzs[64];
    __shared__ int scratch_i[512];    // union: part (u64[128]) then hist (int[512])
    unsigned long long* part = (unsigned long long*)scratch_i;
    int* hist = scratch_i;

    int t = threadIdx.x;
    int w = t >> 6, lane = t & 63;
    int rg = lane >> 3, cg = lane & 7;
    int row0 = blockIdx.x * 64;

    const float4* zg4 = (const float4*)(z + (size_t)row0 * 64);
    const float4* cb4 = (const float4*)cb;
    float4* zs4 = (float4*)zs;   // stride 17 f4
    float4* cbs4 = (float4*)cbs;

    // stage z tile (64 rows x 16 f4)
    for (int i = t; i < 1024; i += 128) {
        int r = i >> 4, c = i & 15;
        zs4[r * 17 + c] = zg4[i - c + c];  // == zg4[i]; rows contiguous
    }
    __syncthreads();
    // per-row ||z||^2, reference fma order (4 partials over f4 components)
    if (t < 64) {
        float a0 = 0, a1 = 0, a2 = 0, a3 = 0;
#pragma unroll
        for (int j = 0; j < 16; ++j) {
            float4 zv = zs4[t * 17 + j];
            a0 = fmaf(zv.x, zv.x, a0);
            a1 = fmaf(zv.y, zv.y, a1);
            a2 = fmaf(zv.z, zv.z, a2);
            a3 = fmaf(zv.w, zv.w, a3);
        }
        zzs[t] = (a0 + a1) + (a2 + a3);
    }

    unsigned bestU[8];
    int bestC[8];
#pragma unroll
    for (int r = 0; r < 8; ++r) { bestU[r] = 0xFFFFFFFFu; bestC[r] = 0; }

    for (int cc = 0; cc < 4; ++cc) {
        __syncthreads();
        // stage 128-code chunk (2048 f4)
        for (int i = t; i < 2048; i += 128) {
            int code = i >> 4, c = i & 15;
            cbs4[code * 17 + c] = cb4[(cc * 128 + code) * 16 + c];
        }
        __syncthreads();

        float acc[8][8];
#pragma unroll
        for (int r = 0; r < 8; ++r)
#pragma unroll
            for (int c = 0; c < 8; ++c) acc[r][c] = 0.f;

        for (int k4 = 0; k4 < 16; ++k4) {
            float4 cbv[8];
#pragma unroll
            for (int c = 0; c < 8; ++c) cbv[c] = cbs4[(w * 64 + cg + 8 * c) * 17 + k4];
#pragma unroll
            for (int r = 0; r < 8; ++r) {
                float4 zv = zs4[(rg + 8 * r) * 17 + k4];
#pragma unroll
                for (int c = 0; c < 8; ++c)
                    acc[r][c] = fmaf(zv.w, cbv[c].w, fmaf(zv.z, cbv[c].z,
                                fmaf(zv.y, cbv[c].y, fmaf(zv.x, cbv[c].x, acc[r][c]))));
            }
        }
        // fold chunk into running per-row best (codes ascend -> strict < keeps lowest)
        float eec[8];
#pragma unroll
        for (int c = 0; c < 8; ++c) eec[c] = ees_g[cc * 128 + w * 64 + cg + 8 * c];
#pragma unroll
        for (int r = 0; r < 8; ++r) {
            float zzr = zzs[rg + 8 * r];
#pragma unroll
            for (int c = 0; c < 8; ++c) {
                float s = fmaf(-2.0f, acc[r][c], zzr + eec[c]);  // == (zz+ee)-2f*dot
                unsigned u = ford(s);
                int code = cc * 128 + w * 64 + cg + 8 * c;
                if (u < bestU[r]) { bestU[r] = u; bestC[r] = code; }
            }
        }
    }

    // cross-cg reduce (cg = low 3 lane bits), lexicographic (score, code)
#pragma unroll
    for (int m = 1; m <= 4; m <<= 1) {
#pragma unroll
        for (int r = 0; r < 8; ++r) {
            unsigned oU = (unsigned)__shfl_xor((int)bestU[r], m);
            int oC = __shfl_xor(bestC[r], m);
            if (oU < bestU[r] || (oU == bestU[r] && oC < bestC[r])) {
                bestU[r] = oU; bestC[r] = oC;
            }
        }
    }
    if (cg == 0) {
#pragma unroll
        for (int r = 0; r < 8; ++r)
            part[(rg + 8 * r) * 2 + w] =
                ((unsigned long long)bestU[r] << 32) | (unsigned)bestC[r];
    }
    __syncthreads();

    int kb = -1;
    double accd = 0.0;
    if (t < 64) {
        unsigned long long b0 = part[t * 2], b1 = part[t * 2 + 1];
        unsigned long long b = b0 < b1 ? b0 : b1;  // min score, then min code
        kb = (int)(b & 0xFFFFFFFFu);
        idx[row0 + t] = kb;
#pragma unroll
        for (int j = 0; j < 16; ++j) {
            float4 qv = cb4[kb * 16 + j];
            float4 zv = zs4[t * 17 + j];
            float fx = qv.x - zv.x, fy = qv.y - zv.y;
            float fz = qv.z - zv.z, fw = qv.w - zv.w;
            accd += (double)fx * fx + (double)fy * fy + (double)fz * fz + (double)fw * fw;
        }
#pragma unroll
        for (int off = 32; off >= 1; off >>= 1) accd += __shfl_down(accd, off);
    }
    __syncthreads();   // part fully consumed; scratch becomes hist
    for (int i = t; i < 512; i += 128) hist[i] = 0;
    __syncthreads();
    if (t == 0) atomicAdd(sse, accd);
    if (t < 64) atomicAdd(&hist[kb], 1);
    __syncthreads();
    for (int i = t; i < 512; i += 128) if (hist[i]) atomicAdd(&counts[i], hist[i]);
}

// ---------------- K3a: cr = codebook @ dec_w ; ees = ||e||^2 ----------------
__global__ __launch_bounds__(256) void k_coderecon(const float* __restrict__ cb,
                                                   const float* __restrict__ dec_w,
                                                   float* __restrict__ cr,
                                                   float* __restrict__ ees_g) {
    __shared__ float wD[64 * 256];  // 64 KB
    __shared__ float qs[32 * 64];   // 8 KB

    int t = threadIdx.x;
    int r0 = blockIdx.x * 32;
    const float4* dw4 = (const float4*)dec_w;
    const float4* cb4 = (const float4*)cb;
    float4* wD4 = (float4*)wD;
#pragma unroll
    for (int j = 0; j < 16; ++j) wD4[t + 256 * j] = dw4[t + 256 * j];
    {
        float4* qs4 = (float4*)qs;
#pragma unroll
        for (int j = 0; j < 2; ++j) qs4[t + 256 * j] = cb4[r0 * 16 + t + 256 * j];
    }
    // ees for this block's 32 codes (reference fma order)
    if (t < 32) {
        float n0 = 0, n1 = 0, n2 = 0, n3 = 0;
#pragma unroll
        for (int j = 0; j < 16; ++j) {
            float4 ev = cb4[(r0 + t) * 16 + j];
            n0 = fmaf(ev.x, ev.x, n0);
            n1 = fmaf(ev.y, ev.y, n1);
            n2 = fmaf(ev.z, ev.z, n2);
            n3 = fmaf(ev.w, ev.w, n3);
        }
        ees_g[r0 + t] = (n0 + n1) + (n2 + n3);
    }
    __syncthreads();

    int l = t & 63, w = t >> 6;
    float4 acc[8];
#pragma unroll
    for (int j = 0; j < 8; ++j) acc[j] = make_float4(0.f, 0.f, 0.f, 0.f);

    for (int d = 0; d < 64; ++d) {
        float4 wv = wD4[d * 64 + l];
#pragma unroll
        for (int j = 0; j < 8; ++j) {
            float q = qs[(w * 8 + j) * 64 + d];
            acc[j].x = fmaf(q, wv.x, acc[j].x);
            acc[j].y = fmaf(q, wv.y, acc[j].y);
            acc[j].z = fmaf(q, wv.z, acc[j].z);
            acc[j].w = fmaf(q, wv.w, acc[j].w);
        }
    }
    float4* cr4 = (float4*)cr;
#pragma unroll
    for (int j = 0; j < 8; ++j) cr4[(size_t)(r0 + w * 8 + j) * 64 + l] = acc[j];
}

// ---------------- K3b: x_recon[row] = cr[idx[row]] (pure gather) ----------------
__global__ __launch_bounds__(256) void k_gather(const float* __restrict__ cr,
                                                const int* __restrict__ idx,
                                                float* __restrict__ out) {
    int t = threadIdx.x;
    int row = blockIdx.x * 16 + (t >> 4);
    int k = idx[row];
    const float4* cr4 = (const float4*)(cr + (size_t)k * 256);
    float* o = out + (size_t)row * 256;
#pragma unroll
    for (int j = 0; j < 4; ++j) {
        int f4 = (t & 15) + 16 * j;
        float4 v = cr4[f4];
        o[f4 * 4 + 0] = v.x;
        o[f4 * 4 + 1] = v.y;
        o[f4 * 4 + 2] = v.z;
        o[f4 * 4 + 3] = v.w;
    }
}

// ---------------- K4: loss + perplexity scalars ----------------
__global__ __launch_bounds__(512) void k_final(const double* __restrict__ sse,
                                               const int* __restrict__ counts,
                                               float* __restrict__ out_loss,
                                               float* __restrict__ out_pp) {
    __shared__ double red[8];
    int t = threadIdx.x;
    double p = (double)counts[t] / 65536.0;
    double term = p * log(p + 1e-10);
#pragma unroll
    for (int off = 32; off >= 1; off >>= 1) term += __shfl_down(term, off);
    if ((t & 63) == 0) red[t >> 6] = term;
    __syncthreads();
    if (t == 0) {
        double s = 0;
#pragma unroll
        for (int w = 0; w < 8; ++w) s += red[w];
        out_pp[0] = (float)exp(-s);
        out_loss[0] = (float)(1.25 * sse[0] / 4194304.0);  // (1+0.25)*mean((q-z)^2)
    }
}

extern "C" void kernel_launch(void* const* d_in, const int* in_sizes, int n_in,
                              void* d_out, int out_size, void* d_ws, size_t ws_size,
                              hipStream_t stream) {
    const float* x = (const float*)d_in[0];
    const float* enc_w = (const float*)d_in[1];
    const float* dec_w = (const float*)d_in[2];
    const float* cb = (const float*)d_in[3];
    float* out = (float*)d_out;

    char* ws = (char*)d_ws;
    float* z = (float*)ws;                        // 16 MiB
    int* idx = (int*)(ws + 16777216);             // 256 KiB
    float* cr = (float*)(ws + 17039360);          // 512 KiB
    double* sse = (double*)(ws + 17563648);       // 8 B
    int* counts = (int*)(ws + 17563656);          // 2 KiB
    float* ees = (float*)(ws + 17565704);         // 2 KiB

    // ws is poisoned to 0xAA before each launch -> zero the accumulators
    hipMemsetAsync(ws + 17563648, 0, 8 + 2048, stream);

    k_coderecon<<<dim3(16), dim3(256), 0, stream>>>(cb, dec_w, cr, ees);
    k_encode<<<dim3(512), dim3(128), 0, stream>>>(x, enc_w, z);
    k_assign<<<dim3(1024), dim3(128), 0, stream>>>(z, cb, ees, idx, sse, counts);
    k_gather<<<dim3(4096), dim3(256), 0, stream>>>(cr, idx, out + 1);
    k_final<<<dim3(1), dim3(512), 0, stream>>>(sse, counts, out, out + 16777217);
}